// Round 11
// baseline (43.809 us; speedup 1.0000x reference)
//
#include <hip/hip_runtime.h>
#include <hip/hip_bf16.h>
#include <math.h>

typedef __attribute__((ext_vector_type(8))) short bf16x8;
typedef __attribute__((ext_vector_type(4))) float f32x4;

#define T_TOT 16384
#define E_ 256
#define FF_ 1024
#define NQ 10
#define TB 64
#define CH 256           // f per chunk
#define NCHUNK (FF_ / CH)
#define HGRAN (TB * CH)  // shorts per hs buffer (16384 = 32 KiB)

// paired f32->bf16 RNE via v_cvt_pk_bf16_f32 (1 VALU per 2 values)
__device__ __forceinline__ unsigned pkbf(float a, float b) {
    __hip_bfloat162 t = __float22bfloat162_rn(make_float2(a, b));
    return *(unsigned*)&t;
}
__device__ __forceinline__ bf16x8 cvt8(float4 a, float4 b) {
    uint4 v;
    v.x = pkbf(a.x, a.y); v.y = pkbf(a.z, a.w);
    v.z = pkbf(b.x, b.y); v.w = pkbf(b.z, b.w);
    return __builtin_bit_cast(bf16x8, v);
}

// ---------------------------------------------------------------------------
// Single fused kernel (v10): no prep kernel, no workspace.
//  - grid 512 = 256 token-tiles x 2 col-halves; 8 waves = 2 wk x 4 wc.
//  - w2 read DIRECTLY in fragment order as fp32 (2x float4/lane), converted
//    in-register with cvt_pk; raw-fp32 depth-1 prefetch across j-steps.
//  - w1 read directly with predicated float2 loads (rows are 40B/8B-aligned).
//  - Everything else identical to R10: analytic q, hs double buffer,
//    split-K waves, setprio around MFMA cluster, LDS reduce, wk=0 stores.
// ---------------------------------------------------------------------------
__global__ __launch_bounds__(512, 4) void ffq_fused(
    const float* __restrict__ x, const float* __restrict__ theta,
    const float* __restrict__ w1, const float* __restrict__ b1,
    const float* __restrict__ w2, const float* __restrict__ b2,
    float* __restrict__ out)
{
    __shared__ unsigned short q_s[4 * 64 * 8];      // 4 KiB
    __shared__ unsigned short hs[2 * HGRAN];        // 64 KiB (double buffer)

    const int tid  = threadIdx.x;
    const int l    = tid & 63;
    const int wv   = tid >> 6;           // 0..7
    const int lr   = l & 15;
    const int g    = l >> 4;             // 0..3
    const int wk   = wv >> 2;            // K-half 0/1
    const int wc   = wv & 3;             // col-pair 0..3
    const int chb  = blockIdx.x & 1;     // col half 0/1
    const int tb   = (blockIdx.x >> 1) * TB;
    const int nc0  = chb * 8 + wc * 2;   // global col-tiles
    const int nc1  = nc0 + 1;

    // per-lane w2 base pointers for the two owned col-tiles (fragment order)
    const float* w2p0 = w2 + (size_t)(nc0 * 16 + lr) * FF_ + g * 8;
    const float* w2p1 = w2 + (size_t)(nc1 * 16 + lr) * FF_ + g * 8;

    // ---- Phase 0: threads 0..63 compute q, write B-frag granules ----
    if (tid < TB) {
        const int t = tb + tid;
        float xv[NQ];
        {
            float4 a = *(const float4*)(x + (size_t)t * E_);
            float4 b = *(const float4*)(x + (size_t)t * E_ + 4);
            float2 c = *(const float2*)(x + (size_t)t * E_ + 8);
            xv[0]=a.x; xv[1]=a.y; xv[2]=a.z; xv[3]=a.w;
            xv[4]=b.x; xv[5]=b.y; xv[6]=b.z; xv[7]=b.w;
            xv[8]=c.x; xv[9]=c.y;
        }
        float mm[NQ];
#pragma unroll
        for (int w = 0; w < NQ; ++w) mm[w] = cosf(theta[w]) * cosf(xv[w]);
        float qv[NQ];
        {
            float p = mm[0];
#pragma unroll
            for (int w = 1; w < NQ; ++w) { p *= mm[w]; qv[w] = p; }
            float p0 = mm[1];
#pragma unroll
            for (int w = 2; w < NQ; ++w) p0 *= mm[w];
            qv[0] = p0;
        }
        uint4 s0, s1;
        s0.x = pkbf(qv[0], qv[1]);
        s0.y = pkbf(qv[2], qv[3]);
        s0.z = pkbf(qv[4], qv[5]);
        s0.w = pkbf(qv[6], qv[7]);
        s1.x = pkbf(qv[8], qv[9]);
        s1.y = 0; s1.z = 0; s1.w = 0;
        int tt = tid >> 4, r = tid & 15;
        uint4* base = (uint4*)q_s + tt * 64;
        base[r]      = s0;
        base[16 + r] = s1;
        base[32 + r] = make_uint4(0, 0, 0, 0);
        base[48 + r] = make_uint4(0, 0, 0, 0);
    }
    __syncthreads();

    f32x4 acc[4][2];
#pragma unroll
    for (int tt = 0; tt < 4; ++tt)
#pragma unroll
        for (int nn = 0; nn < 2; ++nn) acc[tt][nn] = (f32x4){0.f,0.f,0.f,0.f};

    // ---- h-phase macro (chunk cc -> buffer hdst); direct w1 loads ----
    // lane's w1 fragment for granule ntg: k = g*8+j (valid k<10), n = ntg*16+lr
#define H_PHASE(cc, hdst)                                                      \
    {                                                                          \
        bf16x8 wfv[2];                                                         \
        _Pragma("unroll")                                                      \
        for (int fi = 0; fi < 2; ++fi) {                                       \
            const int ntg = (cc) * 16 + wv * 2 + fi;                           \
            const float* row = w1 + (size_t)(ntg * 16 + lr) * NQ;              \
            float4 wa = {0.f,0.f,0.f,0.f}, wb = {0.f,0.f,0.f,0.f};             \
            if (g == 0) {                                                      \
                float2 p0 = *(const float2*)(row + 0);                         \
                float2 p1 = *(const float2*)(row + 2);                         \
                float2 p2 = *(const float2*)(row + 4);                         \
                float2 p3 = *(const float2*)(row + 6);                         \
                wa = make_float4(p0.x, p0.y, p1.x, p1.y);                      \
                wb = make_float4(p2.x, p2.y, p3.x, p3.y);                      \
            } else if (g == 1) {                                               \
                float2 p0 = *(const float2*)(row + 8);                         \
                wa.x = p0.x; wa.y = p0.y;                                      \
            }                                                                  \
            wfv[fi] = cvt8(wa, wb);                                            \
        }                                                                      \
        float4 bba = *(const float4*)(b1 + ((cc) * 16 + wv * 2 + 0) * 16 + g * 4); \
        float4 bbb = *(const float4*)(b1 + ((cc) * 16 + wv * 2 + 1) * 16 + g * 4); \
        bf16x8 qfr[4];                                                         \
        _Pragma("unroll")                                                      \
        for (int tt = 0; tt < 4; ++tt)                                         \
            qfr[tt] = ((const bf16x8*)q_s)[tt * 64 + l];                       \
        _Pragma("unroll")                                                      \
        for (int fi = 0; fi < 2; ++fi) {                                       \
            const int ftl = wv * 2 + fi;                                       \
            float4 bb = fi ? bbb : bba;                                        \
            const int fl   = ftl * 16 + g * 4;                                 \
            const int sl   = (fl & 31) >> 3;                                   \
            const int gran = (fl >> 5) * 64 + lr + 16 * sl;                    \
            _Pragma("unroll")                                                  \
            for (int tt = 0; tt < 4; ++tt) {                                   \
                f32x4 d = {0.f, 0.f, 0.f, 0.f};                                \
                d = __builtin_amdgcn_mfma_f32_16x16x32_bf16(                   \
                        wfv[fi], qfr[tt], d, 0, 0, 0);                         \
                unsigned p0 = pkbf(fmaxf(d[0] + bb.x, 0.f),                    \
                                   fmaxf(d[1] + bb.y, 0.f));                   \
                unsigned p1 = pkbf(fmaxf(d[2] + bb.z, 0.f),                    \
                                   fmaxf(d[3] + bb.w, 0.f));                   \
                unsigned byteoff = (unsigned)(tt * 512 + gran) * 16u           \
                                 + (unsigned)(fl & 7) * 2u;                    \
                *(uint2*)((char*)(hdst) + byteoff) = make_uint2(p0, p1);       \
            }                                                                  \
        }                                                                      \
    }

    // ---- one out-step: convert prev-loaded raw B, issue next raw loads ----
#define OUT_STEP(J)                                                            \
    {                                                                          \
        const int kk  = c * 8 + wk * 4 + (J);                                  \
        const int kkn = ((J) < 3) ? kk + 1 : ((c < NCHUNK - 1) ? kk + 5 : kk); \
        bf16x8 bc0 = cvt8(br0a, br0b);                                         \
        bf16x8 bc1 = cvt8(br1a, br1b);                                         \
        br0a = *(const float4*)(w2p0 + kkn * 32);                              \
        br0b = *(const float4*)(w2p0 + kkn * 32 + 4);                          \
        br1a = *(const float4*)(w2p1 + kkn * 32);                              \
        br1b = *(const float4*)(w2p1 + kkn * 32 + 4);                          \
        bf16x8 af[4];                                                          \
        _Pragma("unroll")                                                      \
        for (int tt = 0; tt < 4; ++tt)                                         \
            af[tt] = hc[(tt * 8 + wk * 4 + (J)) * 64 + l];                     \
        _Pragma("unroll")                                                      \
        for (int tt = 0; tt < 4; ++tt)                                         \
            acc[tt][0] = __builtin_amdgcn_mfma_f32_16x16x32_bf16(              \
                af[tt], bc0, acc[tt][0], 0, 0, 0);                             \
        _Pragma("unroll")                                                      \
        for (int tt = 0; tt < 4; ++tt)                                         \
            acc[tt][1] = __builtin_amdgcn_mfma_f32_16x16x32_bf16(              \
                af[tt], bc1, acc[tt][1], 0, 0, 0);                             \
    }

    // ---- prologue: chunk 0 h-phase into buf0; init raw B prefetch ----
    H_PHASE(0, hs)
    float4 br0a = *(const float4*)(w2p0 + (wk * 4) * 32);
    float4 br0b = *(const float4*)(w2p0 + (wk * 4) * 32 + 4);
    float4 br1a = *(const float4*)(w2p1 + (wk * 4) * 32);
    float4 br1b = *(const float4*)(w2p1 + (wk * 4) * 32 + 4);
    __syncthreads();

    for (int c = 0; c < NCHUNK; ++c) {
        const bf16x8*   hc = (const bf16x8*)(hs + (c & 1) * HGRAN);
        unsigned short* hn = hs + ((c & 1) ^ 1) * HGRAN;

        __builtin_amdgcn_s_setprio(1);
        OUT_STEP(0)
        OUT_STEP(1)
        OUT_STEP(2)
        OUT_STEP(3)
        __builtin_amdgcn_s_setprio(0);

        if (c < NCHUNK - 1) {
            H_PHASE(c + 1, hn)
        }
        __syncthreads();
    }
#undef OUT_STEP
#undef H_PHASE

    // ---- split-K reduce via LDS (stride 36 floats: 16B-aligned, clean) ----
    float* pbuf = (float*)hs;
    const int idx = wc * 64 + l;     // 0..255, shared by wk=0/1 partners
    if (wk == 1) {
#pragma unroll
        for (int tt = 0; tt < 4; ++tt) {
            *(f32x4*)&pbuf[idx * 36 + tt * 8]     = acc[tt][0];
            *(f32x4*)&pbuf[idx * 36 + tt * 8 + 4] = acc[tt][1];
        }
    }
    __syncthreads();
    if (wk == 0) {
#pragma unroll
        for (int tt = 0; tt < 4; ++tt) {
            f32x4 p0 = *(const f32x4*)&pbuf[idx * 36 + tt * 8];
            f32x4 p1 = *(const f32x4*)&pbuf[idx * 36 + tt * 8 + 4];
#pragma unroll
            for (int r = 0; r < 4; ++r) { acc[tt][0][r] += p0[r]; acc[tt][1][r] += p1[r]; }
        }

        // ---- epilogue: + b2, store fp32 ----
#pragma unroll
        for (int nn = 0; nn < 2; ++nn) {
            const int col = (nc0 + nn) * 16 + lr;
            const float bbv = b2[col];
#pragma unroll
            for (int tt = 0; tt < 4; ++tt) {
#pragma unroll
                for (int r = 0; r < 4; ++r) {
                    int tr = tb + tt * 16 + g * 4 + r;
                    out[(size_t)tr * E_ + col] = acc[tt][nn][r] + bbv;
                }
            }
        }
    }
}

extern "C" void kernel_launch(void* const* d_in, const int* in_sizes, int n_in,
                              void* d_out, int out_size, void* d_ws, size_t ws_size,
                              hipStream_t stream) {
    const float* x     = (const float*)d_in[0];
    const float* theta = (const float*)d_in[1];
    const float* w1    = (const float*)d_in[2];
    const float* b1    = (const float*)d_in[3];
    const float* w2    = (const float*)d_in[4];
    const float* b2    = (const float*)d_in[5];
    float* out = (float*)d_out;

    hipLaunchKernelGGL(ffq_fused, dim3(2 * T_TOT / TB), dim3(512), 0, stream,
                       x, theta, w1, b1, w2, b2, out);
}

// Round 12
// 28.162 us; speedup vs baseline: 1.5556x; 1.5556x over previous
//
#include <hip/hip_runtime.h>
#include <hip/hip_bf16.h>
#include <math.h>

typedef __attribute__((ext_vector_type(8))) short bf16x8;
typedef __attribute__((ext_vector_type(4))) float f32x4;

#define T_TOT 16384
#define E_ 256
#define FF_ 1024
#define NQ 10
#define TB 128           // tokens per block
#define CH 128           // f per chunk
#define NCHUNK (FF_ / CH)
#define HGRAN (TB * CH)  // shorts per hs buffer (16384 = 32 KiB)

// paired f32->bf16 RNE via v_cvt_pk_bf16_f32 (1 VALU per 2 values)
__device__ __forceinline__ unsigned pkbf(float a, float b) {
    __hip_bfloat162 t = __float22bfloat162_rn(make_float2(a, b));
    return *(unsigned*)&t;
}

// ---------------------------------------------------------------------------
// Prep (coalesced): bf16 MFMA B-fragments for w2 and w1^T.  (unchanged)
// ---------------------------------------------------------------------------
__global__ __launch_bounds__(256) void ffq_prep(
    const float* __restrict__ w2, const float* __restrict__ w1,
    uint4* __restrict__ w2f, uint4* __restrict__ w1f)
{
    int id = blockIdx.x * 256 + threadIdx.x;
    if (id < 32768) {
        int n  = id >> 7;
        int k0 = (id & 127) * 8;
        const float4* s = (const float4*)(w2 + (size_t)n * FF_ + k0);
        float4 a = s[0], b = s[1];
        uint4 v;
        v.x = pkbf(a.x, a.y);
        v.y = pkbf(a.z, a.w);
        v.z = pkbf(b.x, b.y);
        v.w = pkbf(b.z, b.w);
        int idx = ((k0 >> 5) * 16 + (n >> 4)) * 64 + ((k0 >> 3) & 3) * 16 + (n & 15);
        w2f[idx] = v;
    } else if (id < 32768 + 4096) {
        int id2 = id - 32768;
        int l = id2 & 63, nt = id2 >> 6;
        int n = nt * 16 + (l & 15);
        int g = l >> 4;
        float o[8];
#pragma unroll
        for (int j = 0; j < 8; ++j) {
            int k = g * 8 + j;
            o[j] = (k < NQ) ? w1[n * NQ + k] : 0.f;
        }
        uint4 v;
        v.x = pkbf(o[0], o[1]);
        v.y = pkbf(o[2], o[3]);
        v.z = pkbf(o[4], o[5]);
        v.w = pkbf(o[6], o[7]);
        w1f[id2] = v;
    }
}

// ---------------------------------------------------------------------------
// Fused kernel v12: TB=128, 1024 threads, 16 waves = tg(2) x wk(2) x wc(4).
//  - B-loads/thread HALVED vs R10 (32 dwordx4); tg-pairs share granules (L1).
//  - h-phase per-thread cost unchanged (1 f-tile x 4 token-tiles per chunk,
//    bias folded into MFMA C-operand).
//  - CH=128, NCHUNK=8, hs double-buffered (64 KiB) + q_s 8 KiB.
//  - split-K (wk) with XOR-swizzled LDS reduce; wk=0 stores.
// ---------------------------------------------------------------------------
__global__ __launch_bounds__(1024, 4) void ffq_mfma(
    const float* __restrict__ x, const float* __restrict__ theta,
    const float* __restrict__ b1, const float* __restrict__ b2,
    const bf16x8* __restrict__ w1f, const bf16x8* __restrict__ w2f,
    float* __restrict__ out)
{
    __shared__ unsigned short q_s[8 * 64 * 8];      // 8 KiB
    __shared__ unsigned short hs[2 * HGRAN];        // 64 KiB (double buffer)

    const int tid  = threadIdx.x;
    const int l    = tid & 63;
    const int wv   = tid >> 6;           // 0..15
    const int lr   = l & 15;
    const int g    = l >> 4;             // 0..3
    const int tg   = wv >> 3;            // token half 0/1
    const int wk   = (wv >> 2) & 1;      // K-half 0/1
    const int wc   = wv & 3;             // col-pair 0..3
    const int ftl  = wv & 7;             // h-phase f-tile 0..7
    const int chb  = blockIdx.x & 1;     // col half 0/1
    const int tb   = (blockIdx.x >> 1) * TB;
    const int nc0  = chb * 8 + wc * 2;   // global col-tiles
    const int nc1  = nc0 + 1;

    // ---- Phase 0: threads 0..127 compute q, write B-frag granules ----
    if (tid < TB) {
        const int t = tb + tid;
        float xv[NQ];
        {
            float4 a = *(const float4*)(x + (size_t)t * E_);
            float4 b = *(const float4*)(x + (size_t)t * E_ + 4);
            float2 c = *(const float2*)(x + (size_t)t * E_ + 8);
            xv[0]=a.x; xv[1]=a.y; xv[2]=a.z; xv[3]=a.w;
            xv[4]=b.x; xv[5]=b.y; xv[6]=b.z; xv[7]=b.w;
            xv[8]=c.x; xv[9]=c.y;
        }
        float mm[NQ];
#pragma unroll
        for (int w = 0; w < NQ; ++w) mm[w] = cosf(theta[w]) * cosf(xv[w]);
        float qv[NQ];
        {
            float p = mm[0];
#pragma unroll
            for (int w = 1; w < NQ; ++w) { p *= mm[w]; qv[w] = p; }
            float p0 = mm[1];
#pragma unroll
            for (int w = 2; w < NQ; ++w) p0 *= mm[w];
            qv[0] = p0;
        }
        uint4 s0, s1;
        s0.x = pkbf(qv[0], qv[1]);
        s0.y = pkbf(qv[2], qv[3]);
        s0.z = pkbf(qv[4], qv[5]);
        s0.w = pkbf(qv[6], qv[7]);
        s1.x = pkbf(qv[8], qv[9]);
        s1.y = 0; s1.z = 0; s1.w = 0;
        int tt = tid >> 4, r = tid & 15;
        uint4* base = (uint4*)q_s + tt * 64;
        base[r]      = s0;
        base[16 + r] = s1;
        base[32 + r] = make_uint4(0, 0, 0, 0);
        base[48 + r] = make_uint4(0, 0, 0, 0);
    }
    __syncthreads();

    f32x4 acc[4][2];
#pragma unroll
    for (int tt = 0; tt < 4; ++tt)
#pragma unroll
        for (int nn = 0; nn < 2; ++nn) acc[tt][nn] = (f32x4){0.f,0.f,0.f,0.f};

    // ---- h-phase: wave handles f-tile ftl, token-tiles tg*4..tg*4+3 ----
    // bias enters as MFMA C-operand (identical arithmetic, fewer VALU).
#define H_PHASE(hdst, WF, BBC)                                                 \
    {                                                                          \
        bf16x8 qfr[4];                                                         \
        _Pragma("unroll")                                                      \
        for (int j = 0; j < 4; ++j)                                            \
            qfr[j] = ((const bf16x8*)q_s)[(tg * 4 + j) * 64 + l];              \
        const int fl   = ftl * 16 + g * 4;                                     \
        const int kkl  = fl >> 5;                                              \
        const int sl   = (fl & 31) >> 3;                                       \
        const int gran = kkl * 64 + lr + 16 * sl;                              \
        _Pragma("unroll")                                                      \
        for (int j = 0; j < 4; ++j) {                                          \
            const int tt = tg * 4 + j;                                         \
            f32x4 d = __builtin_amdgcn_mfma_f32_16x16x32_bf16(                 \
                    (WF), qfr[j], (BBC), 0, 0, 0);                             \
            unsigned p0 = pkbf(fmaxf(d[0], 0.f), fmaxf(d[1], 0.f));            \
            unsigned p1 = pkbf(fmaxf(d[2], 0.f), fmaxf(d[3], 0.f));            \
            unsigned byteoff = (unsigned)(tt * 256 + gran) * 16u               \
                             + (unsigned)(fl & 7) * 2u;                        \
            *(uint2*)((char*)(hdst) + byteoff) = make_uint2(p0, p1);           \
        }                                                                      \
    }

    // ---- one out-step: A in-step, B depth-1 register prefetch ----
#define OUT_STEP(J)                                                            \
    {                                                                          \
        const int kk  = c * 4 + wk * 2 + (J);                                  \
        const int kkn = ((J) == 0) ? kk + 1                                    \
                      : ((c < NCHUNK - 1) ? kk + 3 : kk);                      \
        bf16x8 bn0 = w2f[(kkn * 16 + nc0) * 64 + l];                           \
        bf16x8 bn1 = w2f[(kkn * 16 + nc1) * 64 + l];                           \
        bf16x8 af[4];                                                          \
        _Pragma("unroll")                                                      \
        for (int j = 0; j < 4; ++j)                                            \
            af[j] = hc[((tg * 4 + j) * 4 + wk * 2 + (J)) * 64 + l];            \
        _Pragma("unroll")                                                      \
        for (int j = 0; j < 4; ++j)                                            \
            acc[j][0] = __builtin_amdgcn_mfma_f32_16x16x32_bf16(               \
                af[j], bc0, acc[j][0], 0, 0, 0);                               \
        _Pragma("unroll")                                                      \
        for (int j = 0; j < 4; ++j)                                            \
            acc[j][1] = __builtin_amdgcn_mfma_f32_16x16x32_bf16(               \
                af[j], bc1, acc[j][1], 0, 0, 0);                               \
        bc0 = bn0; bc1 = bn1;                                                  \
    }

    // ---- prologue: chunk 0 h-phase into buf0; init B prefetch ----
    bf16x8 wfc = w1f[(0 * 8 + ftl) * 64 + l];
    f32x4  bbc = *(const f32x4*)(b1 + (0 * 8 + ftl) * 16 + g * 4);
    H_PHASE(hs, wfc, bbc)
    bf16x8 bc0 = w2f[((wk * 2) * 16 + nc0) * 64 + l];
    bf16x8 bc1 = w2f[((wk * 2) * 16 + nc1) * 64 + l];
    __syncthreads();

    for (int c = 0; c < NCHUNK; ++c) {
        const bf16x8*   hc = (const bf16x8*)(hs + (c & 1) * HGRAN);
        unsigned short* hn = hs + ((c & 1) ^ 1) * HGRAN;

        // issue next chunk's h-inputs early (land during MFMA cluster)
        if (c < NCHUNK - 1) {
            wfc = w1f[((c + 1) * 8 + ftl) * 64 + l];
            bbc = *(const f32x4*)(b1 + ((c + 1) * 8 + ftl) * 16 + g * 4);
        }

        __builtin_amdgcn_s_setprio(1);
        OUT_STEP(0)
        OUT_STEP(1)
        __builtin_amdgcn_s_setprio(0);

        if (c < NCHUNK - 1) {
            H_PHASE(hn, wfc, bbc)
        }
        __syncthreads();
    }
#undef OUT_STEP
#undef H_PHASE

    // ---- split-K reduce via LDS (XOR-swizzled 16B slots, rule G4) ----
    char* pbuf = (char*)hs;
    const int idx = (tg * 4 + wc) * 64 + l;          // 0..511, wk-invariant
    if (wk == 1) {
#pragma unroll
        for (int j = 0; j < 4; ++j)
#pragma unroll
            for (int nn = 0; nn < 2; ++nn) {
                unsigned k = j * 2 + nn;
                unsigned off = (unsigned)idx * 128u + ((k * 16u) ^ ((idx & 7) << 4));
                *(f32x4*)(pbuf + off) = acc[j][nn];
            }
    }
    __syncthreads();
    if (wk == 0) {
#pragma unroll
        for (int j = 0; j < 4; ++j)
#pragma unroll
            for (int nn = 0; nn < 2; ++nn) {
                unsigned k = j * 2 + nn;
                unsigned off = (unsigned)idx * 128u + ((k * 16u) ^ ((idx & 7) << 4));
                f32x4 p = *(const f32x4*)(pbuf + off);
#pragma unroll
                for (int r = 0; r < 4; ++r) acc[j][nn][r] += p[r];
            }

        // ---- epilogue: + b2, store fp32 ----
#pragma unroll
        for (int nn = 0; nn < 2; ++nn) {
            const int col = (nc0 + nn) * 16 + lr;
            const float bbv = b2[col];
#pragma unroll
            for (int j = 0; j < 4; ++j) {
#pragma unroll
                for (int r = 0; r < 4; ++r) {
                    int tr = tb + (tg * 4 + j) * 16 + g * 4 + r;
                    out[(size_t)tr * E_ + col] = acc[j][nn][r] + bbv;
                }
            }
        }
    }
}

extern "C" void kernel_launch(void* const* d_in, const int* in_sizes, int n_in,
                              void* d_out, int out_size, void* d_ws, size_t ws_size,
                              hipStream_t stream) {
    const float* x     = (const float*)d_in[0];
    const float* theta = (const float*)d_in[1];
    const float* w1    = (const float*)d_in[2];
    const float* b1    = (const float*)d_in[3];
    const float* w2    = (const float*)d_in[4];
    const float* b2    = (const float*)d_in[5];
    float* out = (float*)d_out;

    uint4* w2f = (uint4*)d_ws;                          // 512 KiB
    uint4* w1f = (uint4*)((char*)d_ws + 512 * 1024);    // 64 KiB

    hipLaunchKernelGGL(ffq_prep, dim3(144), dim3(256), 0, stream,
                       w2, w1, w2f, w1f);
    hipLaunchKernelGGL(ffq_mfma, dim3(2 * T_TOT / TB), dim3(1024), 0, stream,
                       x, theta, b1, b2,
                       (const bf16x8*)w1f, (const bf16x8*)w2f, out);
}